// Round 3
// baseline (2445.470 us; speedup 1.0000x reference)
//
#include <hip/hip_runtime.h>
#include <math.h>

#define N_NODES 50000
#define N_EDGES 500000

__device__ __forceinline__ float gelu_tanh(float x) {
    const float k0 = 0.7978845608028654f;
    const float k1 = 0.044715f;
    float inner = k0 * (x + k1 * x * x * x);
    return 0.5f * x * (1.0f + tanhf(inner));
}

// K1: per-node lift.
// feat[n*128 + u*4 + {0,1,2,3}] = {feat_s[u], feat_v[u][x], feat_v[u][y], feat_v[u][z]}
// a*self -> d_out (all 128)
__global__ void node_pre(const float* __restrict__ node_input,
                         const float* __restrict__ W1_s,
                         const float* __restrict__ W1_v,
                         float* __restrict__ feat,
                         float* __restrict__ out) {
    __shared__ float lWs[32 * 64];
    __shared__ float lWv[32 * 64];
    for (int i = threadIdx.x; i < 2048; i += blockDim.x) {
        lWs[i] = W1_s[i];
        lWv[i] = W1_v[i];
    }
    __syncthreads();
    int n = blockIdx.x * blockDim.x + threadIdx.x;
    if (n >= N_NODES) return;
    const float inv_sqrt_mul = 0.17677669529663687f;  // 1/sqrt(32)
    const float a_mix = 0.9219544457292887f;          // sqrt(0.85)

    float s[32];
#pragma unroll
    for (int u = 0; u < 32; ++u) s[u] = node_input[n * 128 + u];
#pragma unroll 4
    for (int w = 0; w < 64; ++w) {
        float acc = 0.f;
#pragma unroll
        for (int u = 0; u < 32; ++u) acc += s[u] * lWs[u * 64 + w];
        acc *= inv_sqrt_mul;
        if (w < 32) feat[(size_t)n * 128 + w * 4 + 0] = acc;
        else        out[n * 128 + (w - 32)] = a_mix * acc;
    }
#pragma unroll
    for (int k = 0; k < 3; ++k) {
        float vk[32];
#pragma unroll
        for (int u = 0; u < 32; ++u) vk[u] = node_input[n * 128 + 32 + u * 3 + k];
#pragma unroll 4
        for (int w = 0; w < 64; ++w) {
            float acc = 0.f;
#pragma unroll
            for (int u = 0; u < 32; ++u) acc += vk[u] * lWv[u * 64 + w];
            acc *= inv_sqrt_mul;
            if (w < 32) feat[(size_t)n * 128 + w * 4 + 1 + k] = acc;
            else        out[n * 128 + 32 + (w - 32) * 3 + k] = a_mix * acc;
        }
    }
}

// K2a: histogram of edge_dst
__global__ void hist_kernel(const int* __restrict__ edge_dst, int* __restrict__ counts) {
    int e = blockIdx.x * blockDim.x + threadIdx.x;
    if (e < N_EDGES) atomicAdd(&counts[edge_dst[e]], 1);
}

// K2b: exclusive scan of counts -> offsets (N+1) and cursor (N). Single block.
__global__ void scan_kernel(const int* __restrict__ counts,
                            int* __restrict__ offsets,
                            int* __restrict__ cursor) {
    const int T = 1024;
    __shared__ int partial[T];
    int t = threadIdx.x;
    const int chunk = (N_NODES + T - 1) / T;  // 49
    int start = t * chunk;
    int end = start + chunk; if (end > N_NODES) end = N_NODES;
    if (start > N_NODES) start = N_NODES;
    int sum = 0;
    for (int i = start; i < end; ++i) sum += counts[i];
    partial[t] = sum;
    __syncthreads();
    for (int off = 1; off < T; off <<= 1) {
        int other = (t >= off) ? partial[t - off] : 0;
        __syncthreads();
        partial[t] += other;
        __syncthreads();
    }
    int run = (t == 0) ? 0 : partial[t - 1];
    for (int i = start; i < end; ++i) {
        offsets[i] = run;
        cursor[i] = run;
        run += counts[i];
    }
    if (t == T - 1) offsets[N_NODES] = run;  // == N_EDGES
}

// K2c: scatter packed edge records into dst-sorted order.
// record (16 floats, 64B): [y0,y1x,y1y,y1z | s0..s3 | s4..s7 | pad x4]; src -> srcs[]
__global__ void scatter_kernel(const int* __restrict__ edge_src,
                               const int* __restrict__ edge_dst,
                               const float* __restrict__ edge_attr,
                               const float* __restrict__ edge_scalars,
                               int* __restrict__ cursor,
                               float* __restrict__ packed,
                               int* __restrict__ srcs) {
    int e = blockIdx.x * blockDim.x + threadIdx.x;
    if (e >= N_EDGES) return;
    int d = edge_dst[e];
    int pos = atomicAdd(&cursor[d], 1);
    float4 a  = *(const float4*)(edge_attr + (size_t)e * 4);
    float4 s0 = *(const float4*)(edge_scalars + (size_t)e * 8);
    float4 s1 = *(const float4*)(edge_scalars + (size_t)e * 8 + 4);
    float4* pf = (float4*)(packed + (size_t)pos * 16);
    pf[0] = a;
    pf[1] = s0;
    pf[2] = s1;
    srcs[pos] = edge_src[e];
}

// K3: per-node conv. One 32-lane group per dst node. Software-pipelined edge loop.
__global__ void conv_kernel(const float* __restrict__ packed,
                            const int* __restrict__ srcs,
                            const int* __restrict__ offsets,
                            const float* __restrict__ M0,
                            const float* __restrict__ M1,
                            const float* __restrict__ Wtp0,
                            const float* __restrict__ Wtp1,
                            const float* __restrict__ Wtp2,
                            const float* __restrict__ Wtp3,
                            const float* __restrict__ W2_s,
                            const float* __restrict__ W2_v,
                            const float* __restrict__ feat,
                            float* __restrict__ out) {
    __shared__ float lM0[8 * 32];
    __shared__ float lM1[32 * 32];
    __shared__ float lW0[32 * 32];
    __shared__ float lW1[32 * 32];
    __shared__ float lW2[32 * 32];
    __shared__ float lW3[32 * 32];
    for (int i = threadIdx.x; i < 256; i += blockDim.x) lM0[i] = M0[i];
    for (int i = threadIdx.x; i < 1024; i += blockDim.x) {
        lM1[i] = M1[i];
        lW0[i] = Wtp0[i];
        lW1[i] = Wtp1[i];
        lW2[i] = Wtp2[i];
        lW3[i] = Wtp3[i];
    }
    __syncthreads();

    const int lane = threadIdx.x & 31;
    const int node = (blockIdx.x * blockDim.x + threadIdx.x) >> 5;
    if (node >= N_NODES) return;

    const float inv_sqrt8  = 0.35355339059327373f;
    const float inv_sqrt32 = 0.17677669529663687f;
    const float INV3 = 0.5773502691896258f;  // 1/sqrt(3)

    const int eb = offsets[node];
    const int ee = offsets[node + 1];

    float a0a = 0.f, a0b = 0.f;
    float a1ax = 0.f, a1ay = 0.f, a1az = 0.f;
    float a1bx = 0.f, a1by = 0.f, a1bz = 0.f;

    if (eb < ee) {
        // pipeline prologue: edge eb fully loaded; src for eb+1 loaded
        float4 ra = *(const float4*)(packed + (size_t)eb * 16);
        float4 rb = *(const float4*)(packed + (size_t)eb * 16 + 4);
        float4 rc = *(const float4*)(packed + (size_t)eb * 16 + 8);
        int s0 = srcs[eb];
        float4 f = *(const float4*)(feat + (size_t)s0 * 128 + lane * 4);
        int e1g = eb + 1 < N_EDGES ? eb + 1 : N_EDGES - 1;
        int sN = srcs[e1g];

        for (int e = eb; e < ee; ++e) {
            // ---- issue prefetches for e+1 / e+2 ----
            int e1 = e + 1 < N_EDGES ? e + 1 : N_EDGES - 1;
            int e2 = e + 2 < N_EDGES ? e + 2 : N_EDGES - 1;
            float4 raN = *(const float4*)(packed + (size_t)e1 * 16);
            float4 rbN = *(const float4*)(packed + (size_t)e1 * 16 + 4);
            float4 rcN = *(const float4*)(packed + (size_t)e1 * 16 + 8);
            float4 fN = *(const float4*)(feat + (size_t)sN * 128 + lane * 4);
            int sNN = srcs[e2];

            // ---- compute edge e ----
            const float y0 = ra.x, y1x = ra.y, y1y = ra.z, y1z = ra.w;
            float t = rb.x * lM0[0 * 32 + lane] + rb.y * lM0[1 * 32 + lane]
                    + rb.z * lM0[2 * 32 + lane] + rb.w * lM0[3 * 32 + lane]
                    + rc.x * lM0[4 * 32 + lane] + rc.y * lM0[5 * 32 + lane]
                    + rc.z * lM0[6 * 32 + lane] + rc.w * lM0[7 * 32 + lane];
            t = gelu_tanh(t * inv_sqrt8);
            float h = 0.f;
#pragma unroll
            for (int m = 0; m < 32; ++m) h += __shfl(t, m, 32) * lM1[m * 32 + lane];
            h = gelu_tanh(h * inv_sqrt32);
            float w0 = 0.f, w1 = 0.f, w2 = 0.f, w3 = 0.f;
#pragma unroll
            for (int j = 0; j < 32; ++j) {
                float hj = __shfl(h, j, 32);
                w0 += hj * lW0[j * 32 + lane];
                w1 += hj * lW1[j * 32 + lane];
                w2 += hj * lW2[j * 32 + lane];
                w3 += hj * lW3[j * 32 + lane];
            }
            w0 *= inv_sqrt32; w1 *= inv_sqrt32; w2 *= inv_sqrt32; w3 *= inv_sqrt32;

            const float es  = f.x;
            const float evx = f.y, evy = f.z, evz = f.w;
            const float dvy = evx * y1x + evy * y1y + evz * y1z;

            a0a += w0 * es * y0;
            a0b += w3 * dvy * INV3;
            const float w1es = w1 * es;
            const float w2y0 = w2 * y0;
            a1ax += w1es * y1x;
            a1ay += w1es * y1y;
            a1az += w1es * y1z;
            a1bx += w2y0 * evx;
            a1by += w2y0 * evy;
            a1bz += w2y0 * evz;

            // ---- rotate pipeline ----
            ra = raN; rb = rbN; rc = rcN; f = fN; sN = sNN;
        }
    }

    // projection: out += sqrt(MIX) * (acc*inv_deg) @ W2 / sqrt(64); W2 from global (L2-hot)
    const float scale = 0.31622776601683794f * 0.125f * 0.3872983346207417f;

    float cs = 0.f, cvx = 0.f, cvy = 0.f, cvz = 0.f;
#pragma unroll
    for (int j = 0; j < 32; ++j) {
        const float va = __shfl(a0a, j, 32);
        const float vb = __shfl(a0b, j, 32);
        cs += va * __ldg(&W2_s[j * 32 + lane]) + vb * __ldg(&W2_s[(32 + j) * 32 + lane]);
        const float vax = __shfl(a1ax, j, 32);
        const float vay = __shfl(a1ay, j, 32);
        const float vaz = __shfl(a1az, j, 32);
        const float vbx = __shfl(a1bx, j, 32);
        const float vby = __shfl(a1by, j, 32);
        const float vbz = __shfl(a1bz, j, 32);
        const float wva = __ldg(&W2_v[j * 32 + lane]);
        const float wvb = __ldg(&W2_v[(32 + j) * 32 + lane]);
        cvx += vax * wva + vbx * wvb;
        cvy += vay * wva + vby * wvb;
        cvz += vaz * wva + vbz * wvb;
    }

    float* o = out + (size_t)node * 128;
    o[lane] += scale * cs;
    o[32 + lane * 3 + 0] += scale * cvx;
    o[32 + lane * 3 + 1] += scale * cvy;
    o[32 + lane * 3 + 2] += scale * cvz;
}

extern "C" void kernel_launch(void* const* d_in, const int* in_sizes, int n_in,
                              void* d_out, int out_size, void* d_ws, size_t ws_size,
                              hipStream_t stream) {
    const float* node_input   = (const float*)d_in[0];
    const float* edge_attr    = (const float*)d_in[1];
    const float* edge_scalars = (const float*)d_in[2];
    const float* W1_s = (const float*)d_in[3];
    const float* W1_v = (const float*)d_in[4];
    const float* M0   = (const float*)d_in[5];
    const float* M1   = (const float*)d_in[6];
    const float* Wtp0 = (const float*)d_in[7];
    const float* Wtp1 = (const float*)d_in[8];
    const float* Wtp2 = (const float*)d_in[9];
    const float* Wtp3 = (const float*)d_in[10];
    const float* W2_s = (const float*)d_in[11];
    const float* W2_v = (const float*)d_in[12];
    const int* edge_src = (const int*)d_in[13];
    const int* edge_dst = (const int*)d_in[14];
    float* out = (float*)d_out;
    float* ws  = (float*)d_ws;

    float* feat   = ws;                                    // N*128 floats (interleaved s/v)
    float* packed = ws + (size_t)N_NODES * 128;            // E*16 floats (64B records)
    int*   srcs    = (int*)(packed + (size_t)N_EDGES * 16); // E
    int*   counts  = srcs + N_EDGES;                        // N
    int*   offsets = counts + N_NODES;                      // N+1
    int*   cursor  = offsets + N_NODES + 1;                 // N
    // total ~60.4 MB

    hipMemsetAsync(counts, 0, N_NODES * sizeof(int), stream);

    node_pre<<<(N_NODES + 255) / 256, 256, 0, stream>>>(node_input, W1_s, W1_v,
                                                        feat, out);

    hist_kernel<<<(N_EDGES + 255) / 256, 256, 0, stream>>>(edge_dst, counts);
    scan_kernel<<<1, 1024, 0, stream>>>(counts, offsets, cursor);
    scatter_kernel<<<(N_EDGES + 255) / 256, 256, 0, stream>>>(edge_src, edge_dst,
                                                              edge_attr, edge_scalars,
                                                              cursor, packed, srcs);

    const int conv_blocks = (N_NODES * 32 + 255) / 256;
    conv_kernel<<<conv_blocks, 256, 0, stream>>>(packed, srcs, offsets,
                                                 M0, M1, Wtp0, Wtp1, Wtp2, Wtp3,
                                                 W2_s, W2_v, feat, out);
}

// Round 4
// 1805.129 us; speedup vs baseline: 1.3547x; 1.3547x over previous
//
#include <hip/hip_runtime.h>
#include <math.h>

#define N_NODES 50000
#define N_EDGES 500000
#define NPB 16      // nodes per conv block (50000 = 16 * 3125 exactly)
#define GROUPS 8    // 32-lane groups per 256-thread block

__device__ __forceinline__ float gelu_tanh(float x) {
    const float k0 = 0.7978845608028654f;
    const float k1 = 0.044715f;
    float inner = k0 * (x + k1 * x * x * x);
    return 0.5f * x * (1.0f + tanhf(inner));
}

// K1: per-node lift.
// feat[n*128 + u*4 + {0..3}] = {feat_s[u], feat_v[u][xyz]} ; a*self -> d_out
__global__ void node_pre(const float* __restrict__ node_input,
                         const float* __restrict__ W1_s,
                         const float* __restrict__ W1_v,
                         float* __restrict__ feat,
                         float* __restrict__ out) {
    __shared__ float lWs[32 * 64];
    __shared__ float lWv[32 * 64];
    for (int i = threadIdx.x; i < 2048; i += blockDim.x) {
        lWs[i] = W1_s[i];
        lWv[i] = W1_v[i];
    }
    __syncthreads();
    int n = blockIdx.x * blockDim.x + threadIdx.x;
    if (n >= N_NODES) return;
    const float inv_sqrt_mul = 0.17677669529663687f;  // 1/sqrt(32)
    const float a_mix = 0.9219544457292887f;          // sqrt(0.85)

    float s[32];
#pragma unroll
    for (int u = 0; u < 32; ++u) s[u] = node_input[n * 128 + u];
#pragma unroll 4
    for (int w = 0; w < 64; ++w) {
        float acc = 0.f;
#pragma unroll
        for (int u = 0; u < 32; ++u) acc += s[u] * lWs[u * 64 + w];
        acc *= inv_sqrt_mul;
        if (w < 32) feat[(size_t)n * 128 + w * 4 + 0] = acc;
        else        out[n * 128 + (w - 32)] = a_mix * acc;
    }
#pragma unroll
    for (int k = 0; k < 3; ++k) {
        float vk[32];
#pragma unroll
        for (int u = 0; u < 32; ++u) vk[u] = node_input[n * 128 + 32 + u * 3 + k];
#pragma unroll 4
        for (int w = 0; w < 64; ++w) {
            float acc = 0.f;
#pragma unroll
            for (int u = 0; u < 32; ++u) acc += vk[u] * lWv[u * 64 + w];
            acc *= inv_sqrt_mul;
            if (w < 32) feat[(size_t)n * 128 + w * 4 + 1 + k] = acc;
            else        out[n * 128 + 32 + (w - 32) * 3 + k] = a_mix * acc;
        }
    }
}

// K2a: histogram of edge_dst
__global__ void hist_kernel(const int* __restrict__ edge_dst, int* __restrict__ counts) {
    int e = blockIdx.x * blockDim.x + threadIdx.x;
    if (e < N_EDGES) atomicAdd(&counts[edge_dst[e]], 1);
}

// K2b: exclusive scan of counts -> offsets (N+1) and cursor (N). Single block.
__global__ void scan_kernel(const int* __restrict__ counts,
                            int* __restrict__ offsets,
                            int* __restrict__ cursor) {
    const int T = 1024;
    __shared__ int partial[T];
    int t = threadIdx.x;
    const int chunk = (N_NODES + T - 1) / T;
    int start = t * chunk;
    int end = start + chunk; if (end > N_NODES) end = N_NODES;
    if (start > N_NODES) start = N_NODES;
    int sum = 0;
    for (int i = start; i < end; ++i) sum += counts[i];
    partial[t] = sum;
    __syncthreads();
    for (int off = 1; off < T; off <<= 1) {
        int other = (t >= off) ? partial[t - off] : 0;
        __syncthreads();
        partial[t] += other;
        __syncthreads();
    }
    int run = (t == 0) ? 0 : partial[t - 1];
    for (int i = start; i < end; ++i) {
        offsets[i] = run;
        cursor[i] = run;
        run += counts[i];
    }
    if (t == T - 1) offsets[N_NODES] = run;  // == N_EDGES
}

// K2c: scatter packed edge records into dst-sorted order.
// record (12 floats, 48B): [y0,y1x,y1y,y1z | s0..s3 | s4..s7]; (src,dst) -> srcdst[]
__global__ void scatter_kernel(const int* __restrict__ edge_src,
                               const int* __restrict__ edge_dst,
                               const float* __restrict__ edge_attr,
                               const float* __restrict__ edge_scalars,
                               int* __restrict__ cursor,
                               float* __restrict__ packed,
                               int2* __restrict__ srcdst) {
    int e = blockIdx.x * blockDim.x + threadIdx.x;
    if (e >= N_EDGES) return;
    int d = edge_dst[e];
    int pos = atomicAdd(&cursor[d], 1);
    float4 a  = *(const float4*)(edge_attr + (size_t)e * 4);
    float4 s0 = *(const float4*)(edge_scalars + (size_t)e * 8);
    float4 s1 = *(const float4*)(edge_scalars + (size_t)e * 8 + 4);
    float* pf = packed + (size_t)pos * 12;
    *(float4*)(pf)     = a;
    *(float4*)(pf + 4) = s0;
    *(float4*)(pf + 8) = s1;
    srcdst[pos] = make_int2(edge_src[e], d);
}

// K3: conv. Each block owns NPB contiguous dst nodes => contiguous edge range.
// 8 independent 32-lane groups stride the edge list; accumulate into LDS with
// ds_add_f32; block epilogue does the W2 projection and one coalesced out +=.
__global__ void __launch_bounds__(256, 4)
conv_kernel(const float* __restrict__ packed,
            const int2* __restrict__ srcdst,
            const int* __restrict__ offsets,
            const float* __restrict__ M0,
            const float* __restrict__ M1,
            const float* __restrict__ Wtp0,
            const float* __restrict__ Wtp1,
            const float* __restrict__ Wtp2,
            const float* __restrict__ Wtp3,
            const float* __restrict__ W2_s,
            const float* __restrict__ W2_v,
            const float* __restrict__ feat,
            float* __restrict__ out) {
    __shared__ float lM0[8 * 32];
    __shared__ float lM1[32 * 32];
    __shared__ float lW0[32 * 32];
    __shared__ float lW1[32 * 32];
    __shared__ float lW2[32 * 32];
    __shared__ float lW3[32 * 32];
    __shared__ float sacc[NPB * 256];  // per-node raw accum: [s(64) | v(3*64)]

    for (int i = threadIdx.x; i < 256; i += blockDim.x) lM0[i] = M0[i];
    for (int i = threadIdx.x; i < 1024; i += blockDim.x) {
        lM1[i] = M1[i];
        lW0[i] = Wtp0[i];
        lW1[i] = Wtp1[i];
        lW2[i] = Wtp2[i];
        lW3[i] = Wtp3[i];
    }
    for (int i = threadIdx.x; i < NPB * 256; i += blockDim.x) sacc[i] = 0.f;
    __syncthreads();

    const int lane = threadIdx.x & 31;
    const int g = threadIdx.x >> 5;
    const int n0 = blockIdx.x * NPB;
    const int eb = offsets[n0];
    const int ee = offsets[n0 + NPB];

    const float inv_sqrt8  = 0.35355339059327373f;
    const float inv_sqrt32 = 0.17677669529663687f;
    const float INV3 = 0.5773502691896258f;  // 1/sqrt(3)

    int e = eb + g;
    if (e < ee) {
        int2 sd = srcdst[e];
        const float* rp = packed + (size_t)e * 12;
        float4 ra = *(const float4*)(rp);
        float4 rb = *(const float4*)(rp + 4);
        float4 rc = *(const float4*)(rp + 8);
        float4 f  = *(const float4*)(feat + (size_t)sd.x * 128 + lane * 4);

        while (true) {
            const int en = e + GROUPS;
            const bool hn = en < ee;
            const int ep = hn ? en : e;
            int2 sdN = srcdst[ep];
            const float* rpN = packed + (size_t)ep * 12;
            float4 raN = *(const float4*)(rpN);
            float4 rbN = *(const float4*)(rpN + 4);
            float4 rcN = *(const float4*)(rpN + 8);
            float4 fN  = *(const float4*)(feat + (size_t)sdN.x * 128 + lane * 4);

            // ---- compute current edge ----
            const float y0 = ra.x, y1x = ra.y, y1y = ra.z, y1z = ra.w;
            float t = rb.x * lM0[0 * 32 + lane] + rb.y * lM0[1 * 32 + lane]
                    + rb.z * lM0[2 * 32 + lane] + rb.w * lM0[3 * 32 + lane]
                    + rc.x * lM0[4 * 32 + lane] + rc.y * lM0[5 * 32 + lane]
                    + rc.z * lM0[6 * 32 + lane] + rc.w * lM0[7 * 32 + lane];
            t = gelu_tanh(t * inv_sqrt8);
            float h = 0.f;
#pragma unroll
            for (int m = 0; m < 32; ++m) h += __shfl(t, m, 32) * lM1[m * 32 + lane];
            h = gelu_tanh(h * inv_sqrt32);
            float w0 = 0.f, w1 = 0.f, w2 = 0.f, w3 = 0.f;
#pragma unroll
            for (int j = 0; j < 32; ++j) {
                float hj = __shfl(h, j, 32);
                w0 += hj * lW0[j * 32 + lane];
                w1 += hj * lW1[j * 32 + lane];
                w2 += hj * lW2[j * 32 + lane];
                w3 += hj * lW3[j * 32 + lane];
            }
            w0 *= inv_sqrt32; w1 *= inv_sqrt32; w2 *= inv_sqrt32; w3 *= inv_sqrt32;

            const float es  = f.x;
            const float evx = f.y, evy = f.z, evz = f.w;
            const float dvy = evx * y1x + evy * y1y + evz * y1z;
            const float w1es = w1 * es;
            const float w2y0 = w2 * y0;

            float* a = sacc + (sd.y - n0) * 256;
            atomicAdd(a + lane,            w0 * es * y0);
            atomicAdd(a + 32 + lane,       w3 * dvy * INV3);
            atomicAdd(a + 64 + lane * 3 + 0,  w1es * y1x);
            atomicAdd(a + 64 + lane * 3 + 1,  w1es * y1y);
            atomicAdd(a + 64 + lane * 3 + 2,  w1es * y1z);
            atomicAdd(a + 160 + lane * 3 + 0, w2y0 * evx);
            atomicAdd(a + 160 + lane * 3 + 1, w2y0 * evy);
            atomicAdd(a + 160 + lane * 3 + 2, w2y0 * evz);

            if (!hn) break;
            e = en; sd = sdN; ra = raN; rb = rbN; rc = rcN; f = fN;
        }
    }
    __syncthreads();

    // epilogue: per node, conv = (acc*inv_deg) @ W2 / sqrt(64); out += sqrt(MIX)*conv
    const float scale = 0.31622776601683794f * 0.125f * 0.3872983346207417f;
    for (int li = g; li < NPB; li += GROUPS) {
        const float* a = sacc + li * 256;
        float cs = 0.f, cv0 = 0.f, cv1 = 0.f, cv2 = 0.f;
#pragma unroll 8
        for (int j = 0; j < 64; ++j) {
            const float as = a[j];                 // LDS broadcast
            cs += as * __ldg(&W2_s[j * 32 + lane]);
            const float wv = __ldg(&W2_v[j * 32 + lane]);
            cv0 += a[64 + 3 * j + 0] * wv;
            cv1 += a[64 + 3 * j + 1] * wv;
            cv2 += a[64 + 3 * j + 2] * wv;
        }
        float* o = out + (size_t)(n0 + li) * 128;
        o[lane]              += scale * cs;
        o[32 + lane * 3 + 0] += scale * cv0;
        o[32 + lane * 3 + 1] += scale * cv1;
        o[32 + lane * 3 + 2] += scale * cv2;
    }
}

extern "C" void kernel_launch(void* const* d_in, const int* in_sizes, int n_in,
                              void* d_out, int out_size, void* d_ws, size_t ws_size,
                              hipStream_t stream) {
    const float* node_input   = (const float*)d_in[0];
    const float* edge_attr    = (const float*)d_in[1];
    const float* edge_scalars = (const float*)d_in[2];
    const float* W1_s = (const float*)d_in[3];
    const float* W1_v = (const float*)d_in[4];
    const float* M0   = (const float*)d_in[5];
    const float* M1   = (const float*)d_in[6];
    const float* Wtp0 = (const float*)d_in[7];
    const float* Wtp1 = (const float*)d_in[8];
    const float* Wtp2 = (const float*)d_in[9];
    const float* Wtp3 = (const float*)d_in[10];
    const float* W2_s = (const float*)d_in[11];
    const float* W2_v = (const float*)d_in[12];
    const int* edge_src = (const int*)d_in[13];
    const int* edge_dst = (const int*)d_in[14];
    float* out = (float*)d_out;
    float* ws  = (float*)d_ws;

    float* feat   = ws;                                      // N*128 floats
    float* packed = ws + (size_t)N_NODES * 128;              // E*12 floats
    int2*  srcdst = (int2*)(packed + (size_t)N_EDGES * 12);  // E int2
    int*   counts  = (int*)(srcdst + N_EDGES);               // N
    int*   offsets = counts + N_NODES;                       // N+1
    int*   cursor  = offsets + N_NODES + 1;                  // N
    // total ~= 25.6 + 24 + 4 + 0.6 MB ~= 54.2 MB

    hipMemsetAsync(counts, 0, N_NODES * sizeof(int), stream);

    node_pre<<<(N_NODES + 255) / 256, 256, 0, stream>>>(node_input, W1_s, W1_v,
                                                        feat, out);

    hist_kernel<<<(N_EDGES + 255) / 256, 256, 0, stream>>>(edge_dst, counts);
    scan_kernel<<<1, 1024, 0, stream>>>(counts, offsets, cursor);
    scatter_kernel<<<(N_EDGES + 255) / 256, 256, 0, stream>>>(edge_src, edge_dst,
                                                              edge_attr, edge_scalars,
                                                              cursor, packed, srcdst);

    conv_kernel<<<N_NODES / NPB, 256, 0, stream>>>(packed, srcdst, offsets,
                                                   M0, M1, Wtp0, Wtp1, Wtp2, Wtp3,
                                                   W2_s, W2_v, feat, out);
}

// Round 5
// 1140.471 us; speedup vs baseline: 2.1443x; 1.5828x over previous
//
#include <hip/hip_runtime.h>
#include <math.h>

#define N_NODES 50000
#define N_EDGES 500000
#define NPB 16      // nodes per conv block (50000 = 16 * 3125)
#define GROUPS 8    // 32-lane groups per 256-thread block

__device__ __forceinline__ float gelu_tanh(float x) {
    const float k0 = 0.7978845608028654f;
    const float k1 = 0.044715f;
    float inner = k0 * (x + k1 * x * x * x);
    return 0.5f * x * (1.0f + tanhf(inner));
}

__device__ __forceinline__ unsigned short f2bf(float x) {
    unsigned int u = __float_as_uint(x);
    unsigned int r = (u + 0x7FFFu + ((u >> 16) & 1u)) >> 16;  // RNE
    return (unsigned short)r;
}
__device__ __forceinline__ float bf2f(unsigned short b) {
    return __uint_as_float(((unsigned int)b) << 16);
}

// K1: per-node lift.
// feat[n*128 + u*4 + {0..3}] = {feat_s[u], feat_v[u][xyz]} ; a*self -> d_out
__global__ void node_pre(const float* __restrict__ node_input,
                         const float* __restrict__ W1_s,
                         const float* __restrict__ W1_v,
                         float* __restrict__ feat,
                         float* __restrict__ out) {
    __shared__ float lWs[32 * 64];
    __shared__ float lWv[32 * 64];
    for (int i = threadIdx.x; i < 2048; i += blockDim.x) {
        lWs[i] = W1_s[i];
        lWv[i] = W1_v[i];
    }
    __syncthreads();
    int n = blockIdx.x * blockDim.x + threadIdx.x;
    if (n >= N_NODES) return;
    const float inv_sqrt_mul = 0.17677669529663687f;  // 1/sqrt(32)
    const float a_mix = 0.9219544457292887f;          // sqrt(0.85)

    float s[32];
#pragma unroll
    for (int u = 0; u < 32; ++u) s[u] = node_input[n * 128 + u];
#pragma unroll 4
    for (int w = 0; w < 64; ++w) {
        float acc = 0.f;
#pragma unroll
        for (int u = 0; u < 32; ++u) acc += s[u] * lWs[u * 64 + w];
        acc *= inv_sqrt_mul;
        if (w < 32) feat[(size_t)n * 128 + w * 4 + 0] = acc;
        else        out[n * 128 + (w - 32)] = a_mix * acc;
    }
#pragma unroll
    for (int k = 0; k < 3; ++k) {
        float vk[32];
#pragma unroll
        for (int u = 0; u < 32; ++u) vk[u] = node_input[n * 128 + 32 + u * 3 + k];
#pragma unroll 4
        for (int w = 0; w < 64; ++w) {
            float acc = 0.f;
#pragma unroll
            for (int u = 0; u < 32; ++u) acc += vk[u] * lWv[u * 64 + w];
            acc *= inv_sqrt_mul;
            if (w < 32) feat[(size_t)n * 128 + w * 4 + 1 + k] = acc;
            else        out[n * 128 + 32 + (w - 32) * 3 + k] = a_mix * acc;
        }
    }
}

// K2a: histogram of edge_dst
__global__ void hist_kernel(const int* __restrict__ edge_dst, int* __restrict__ counts) {
    int e = blockIdx.x * blockDim.x + threadIdx.x;
    if (e < N_EDGES) atomicAdd(&counts[edge_dst[e]], 1);
}

// K2b: exclusive scan of counts -> offsets (N+1) and cursor (N). Single block.
__global__ void scan_kernel(const int* __restrict__ counts,
                            int* __restrict__ offsets,
                            int* __restrict__ cursor) {
    const int T = 1024;
    __shared__ int partial[T];
    int t = threadIdx.x;
    const int chunk = (N_NODES + T - 1) / T;
    int start = t * chunk;
    int end = start + chunk; if (end > N_NODES) end = N_NODES;
    if (start > N_NODES) start = N_NODES;
    int sum = 0;
    for (int i = start; i < end; ++i) sum += counts[i];
    partial[t] = sum;
    __syncthreads();
    for (int off = 1; off < T; off <<= 1) {
        int other = (t >= off) ? partial[t - off] : 0;
        __syncthreads();
        partial[t] += other;
        __syncthreads();
    }
    int run = (t == 0) ? 0 : partial[t - 1];
    for (int i = start; i < end; ++i) {
        offsets[i] = run;
        cursor[i] = run;
        run += counts[i];
    }
    if (t == T - 1) offsets[N_NODES] = run;  // == N_EDGES
}

// K2c: scatter edge data into dst-sorted order.
// sS4[pos*2 + {0,1}] = scalars (8 floats); ySorted[pos] = edge_attr (float4);
// srcdst[pos] = (src, dst)
__global__ void scatter_kernel(const int* __restrict__ edge_src,
                               const int* __restrict__ edge_dst,
                               const float* __restrict__ edge_attr,
                               const float* __restrict__ edge_scalars,
                               int* __restrict__ cursor,
                               float4* __restrict__ sS4,
                               float4* __restrict__ ySorted,
                               int2* __restrict__ srcdst) {
    int e = blockIdx.x * blockDim.x + threadIdx.x;
    if (e >= N_EDGES) return;
    int d = edge_dst[e];
    int pos = atomicAdd(&cursor[d], 1);
    float4 a  = *(const float4*)(edge_attr + (size_t)e * 4);
    float4 s0 = *(const float4*)(edge_scalars + (size_t)e * 8);
    float4 s1 = *(const float4*)(edge_scalars + (size_t)e * 8 + 4);
    ySorted[pos] = a;
    sS4[(size_t)pos * 2 + 0] = s0;
    sS4[(size_t)pos * 2 + 1] = s1;
    srcdst[pos] = make_int2(edge_src[e], d);
}

// K_mlp: one THREAD per sorted edge. Transposed float4 weights in LDS
// (uniform broadcast reads). Writes w0..w3 per channel as bf16x4 (8B).
__global__ void mlp_kernel(const float4* __restrict__ sS4,
                           const float* __restrict__ M0,
                           const float* __restrict__ M1,
                           const float* __restrict__ Wtp0,
                           const float* __restrict__ Wtp1,
                           const float* __restrict__ Wtp2,
                           const float* __restrict__ Wtp3,
                           ushort4* __restrict__ wOut) {
    __shared__ float lM0t[32 * 8];        // [u][i]
    __shared__ float lM1t[32 * 32];       // [u][m]
    __shared__ float lWt[32 * 32 * 4];    // [u][j][c], c = which Wtp

    for (int idx = threadIdx.x; idx < 256; idx += blockDim.x) {
        int i = idx >> 5, u = idx & 31;
        lM0t[u * 8 + i] = M0[idx];
    }
    for (int idx = threadIdx.x; idx < 1024; idx += blockDim.x) {
        int m = idx >> 5, u = idx & 31;
        lM1t[u * 32 + m] = M1[idx];
        int base = (u * 32 + m) * 4;
        lWt[base + 0] = Wtp0[idx];
        lWt[base + 1] = Wtp1[idx];
        lWt[base + 2] = Wtp2[idx];
        lWt[base + 3] = Wtp3[idx];
    }
    __syncthreads();

    const int e = blockIdx.x * blockDim.x + threadIdx.x;
    if (e >= N_EDGES) return;

    const float inv_sqrt8  = 0.35355339059327373f;
    const float inv_sqrt32 = 0.17677669529663687f;

    const float4 s0 = sS4[(size_t)e * 2 + 0];
    const float4 s1 = sS4[(size_t)e * 2 + 1];
    const float4* lM0t4 = (const float4*)lM0t;
    const float4* lM1t4 = (const float4*)lM1t;
    const float4* lWt4  = (const float4*)lWt;

    // layer 1: t[32]
    float t[32];
#pragma unroll
    for (int u = 0; u < 32; ++u) {
        float4 a = lM0t4[u * 2 + 0];
        float4 b = lM0t4[u * 2 + 1];
        float acc = a.x * s0.x + a.y * s0.y + a.z * s0.z + a.w * s0.w
                  + b.x * s1.x + b.y * s1.y + b.z * s1.z + b.w * s1.w;
        t[u] = gelu_tanh(acc * inv_sqrt8);
    }
    // layer 2: h[32]
    float h[32];
#pragma unroll
    for (int u = 0; u < 32; ++u) {
        float acc = 0.f;
#pragma unroll
        for (int j = 0; j < 8; ++j) {
            float4 mm = lM1t4[u * 8 + j];
            acc += mm.x * t[4 * j + 0] + mm.y * t[4 * j + 1]
                 + mm.z * t[4 * j + 2] + mm.w * t[4 * j + 3];
        }
        h[u] = gelu_tanh(acc * inv_sqrt32);
    }
    // layer 3: w0..w3 per u, write bf16x4
    ushort4* wbase = wOut + (size_t)e * 32;
#pragma unroll 1
    for (int u = 0; u < 32; ++u) {
        float ax = 0.f, ay = 0.f, az = 0.f, aw = 0.f;
#pragma unroll
        for (int j = 0; j < 32; ++j) {
            float4 wv = lWt4[u * 32 + j];
            float hj = h[j];
            ax += hj * wv.x; ay += hj * wv.y; az += hj * wv.z; aw += hj * wv.w;
        }
        ushort4 o;
        o.x = f2bf(ax * inv_sqrt32);
        o.y = f2bf(ay * inv_sqrt32);
        o.z = f2bf(az * inv_sqrt32);
        o.w = f2bf(aw * inv_sqrt32);
        wbase[u] = o;
    }
}

// K_conv: block owns NPB contiguous dst nodes => contiguous edge range.
// Per edge-lane: 3 loads + ~15 FMA + 8 LDS atomics. Tiny register/LDS footprint.
__global__ void __launch_bounds__(256)
conv_kernel(const ushort4* __restrict__ wOut,
            const float4* __restrict__ ySorted,
            const int2* __restrict__ srcdst,
            const int* __restrict__ offsets,
            const float* __restrict__ W2_s,
            const float* __restrict__ W2_v,
            const float* __restrict__ feat,
            float* __restrict__ out) {
    __shared__ float sacc[NPB * 256];  // per-node raw accum: [s(64) | v(3*64)]
    for (int i = threadIdx.x; i < NPB * 256; i += blockDim.x) sacc[i] = 0.f;
    __syncthreads();

    const int lane = threadIdx.x & 31;
    const int g = threadIdx.x >> 5;
    const int n0 = blockIdx.x * NPB;
    const int eb = offsets[n0];
    const int ee = offsets[n0 + NPB];
    const float INV3 = 0.5773502691896258f;  // 1/sqrt(3)
    const float4* feat4 = (const float4*)feat;

#pragma unroll 2
    for (int e = eb + g; e < ee; e += GROUPS) {
        const int2 sd = srcdst[e];
        const ushort4 wq = wOut[(size_t)e * 32 + lane];
        const float4 yq = ySorted[e];                  // uniform per group
        const float4 f = feat4[(size_t)sd.x * 32 + lane];

        const float w0 = bf2f(wq.x), w1 = bf2f(wq.y);
        const float w2 = bf2f(wq.z), w3 = bf2f(wq.w);
        const float dvy = f.y * yq.y + f.z * yq.z + f.w * yq.w;
        const float w1es = w1 * f.x;
        const float w2y0 = w2 * yq.x;

        float* a = sacc + (sd.y - n0) * 256;
        atomicAdd(a + lane,               w0 * f.x * yq.x);
        atomicAdd(a + 32 + lane,          w3 * dvy * INV3);
        atomicAdd(a + 64 + lane * 3 + 0,  w1es * yq.y);
        atomicAdd(a + 64 + lane * 3 + 1,  w1es * yq.z);
        atomicAdd(a + 64 + lane * 3 + 2,  w1es * yq.w);
        atomicAdd(a + 160 + lane * 3 + 0, w2y0 * f.y);
        atomicAdd(a + 160 + lane * 3 + 1, w2y0 * f.z);
        atomicAdd(a + 160 + lane * 3 + 2, w2y0 * f.w);
    }
    __syncthreads();

    // epilogue: per node, conv = (acc*inv_deg) @ W2 / sqrt(64); out += sqrt(MIX)*conv
    const float scale = 0.31622776601683794f * 0.125f * 0.3872983346207417f;
    for (int li = g; li < NPB; li += GROUPS) {
        const float* a = sacc + li * 256;
        float cs = 0.f, cv0 = 0.f, cv1 = 0.f, cv2 = 0.f;
#pragma unroll 8
        for (int j = 0; j < 64; ++j) {
            const float as = a[j];                 // LDS broadcast
            cs += as * __ldg(&W2_s[j * 32 + lane]);
            const float wv = __ldg(&W2_v[j * 32 + lane]);
            cv0 += a[64 + 3 * j + 0] * wv;
            cv1 += a[64 + 3 * j + 1] * wv;
            cv2 += a[64 + 3 * j + 2] * wv;
        }
        float* o = out + (size_t)(n0 + li) * 128;
        o[lane]              += scale * cs;
        o[32 + lane * 3 + 0] += scale * cv0;
        o[32 + lane * 3 + 1] += scale * cv1;
        o[32 + lane * 3 + 2] += scale * cv2;
    }
}

extern "C" void kernel_launch(void* const* d_in, const int* in_sizes, int n_in,
                              void* d_out, int out_size, void* d_ws, size_t ws_size,
                              hipStream_t stream) {
    const float* node_input   = (const float*)d_in[0];
    const float* edge_attr    = (const float*)d_in[1];
    const float* edge_scalars = (const float*)d_in[2];
    const float* W1_s = (const float*)d_in[3];
    const float* W1_v = (const float*)d_in[4];
    const float* M0   = (const float*)d_in[5];
    const float* M1   = (const float*)d_in[6];
    const float* Wtp0 = (const float*)d_in[7];
    const float* Wtp1 = (const float*)d_in[8];
    const float* Wtp2 = (const float*)d_in[9];
    const float* Wtp3 = (const float*)d_in[10];
    const float* W2_s = (const float*)d_in[11];
    const float* W2_v = (const float*)d_in[12];
    const int* edge_src = (const int*)d_in[13];
    const int* edge_dst = (const int*)d_in[14];
    float* out = (float*)d_out;
    float* ws  = (float*)d_ws;

    // workspace layout (floats):
    float*  feat    = ws;                                   // N*128       (25.6 MB)
    float4* sS4     = (float4*)(feat + (size_t)N_NODES * 128);      // E*2 float4 (16 MB)
    float4* ySorted = sS4 + (size_t)N_EDGES * 2;            // E float4    (8 MB)
    ushort4* wOut   = (ushort4*)(ySorted + N_EDGES);        // E*32 ushort4 (64 MB)
    int2*  srcdst   = (int2*)(wOut + (size_t)N_EDGES * 32); // E int2      (4 MB)
    int*   counts   = (int*)(srcdst + N_EDGES);             // N
    int*   offsets  = counts + N_NODES;                     // N+1
    int*   cursor   = offsets + N_NODES + 1;                // N
    // total ~118 MB

    hipMemsetAsync(counts, 0, N_NODES * sizeof(int), stream);

    node_pre<<<(N_NODES + 255) / 256, 256, 0, stream>>>(node_input, W1_s, W1_v,
                                                        feat, out);

    hist_kernel<<<(N_EDGES + 255) / 256, 256, 0, stream>>>(edge_dst, counts);
    scan_kernel<<<1, 1024, 0, stream>>>(counts, offsets, cursor);
    scatter_kernel<<<(N_EDGES + 255) / 256, 256, 0, stream>>>(edge_src, edge_dst,
                                                              edge_attr, edge_scalars,
                                                              cursor, sS4, ySorted, srcdst);

    mlp_kernel<<<(N_EDGES + 255) / 256, 256, 0, stream>>>(sS4, M0, M1,
                                                          Wtp0, Wtp1, Wtp2, Wtp3, wOut);

    conv_kernel<<<N_NODES / NPB, 256, 0, stream>>>(wOut, ySorted, srcdst, offsets,
                                                   W2_s, W2_v, feat, out);
}

// Round 6
// 554.708 us; speedup vs baseline: 4.4086x; 2.0560x over previous
//
#include <hip/hip_runtime.h>
#include <math.h>

#define N_NODES 50000
#define N_EDGES 500000
#define NPB 16      // nodes per conv block (50000 = 16 * 3125)
#define GROUPS 8    // 32-lane groups per 256-thread block

__device__ __forceinline__ float gelu_tanh(float x) {
    const float k0 = 0.7978845608028654f;
    const float k1 = 0.044715f;
    float inner = k0 * (x + k1 * x * x * x);
    return 0.5f * x * (1.0f + tanhf(inner));
}

__device__ __forceinline__ unsigned short f2bf(float x) {
    unsigned int u = __float_as_uint(x);
    unsigned int r = (u + 0x7FFFu + ((u >> 16) & 1u)) >> 16;  // RNE
    return (unsigned short)r;
}
__device__ __forceinline__ float bf2f(unsigned short b) {
    return __uint_as_float(((unsigned int)b) << 16);
}

// Fire-and-forget native LDS float add (no CAS loop, no return).
// Generic pointers to LDS on gfx9+ carry the LDS byte offset in the low 32 bits.
__device__ __forceinline__ void lds_add(float* p, float v) {
    unsigned int off = (unsigned int)(size_t)p;
    asm volatile("ds_add_f32 %0, %1" :: "v"(off), "v"(v) : "memory");
}

// K1: per-node lift.
// feat[n*128 + u*4 + {0..3}] = {feat_s[u], feat_v[u][xyz]} ; a*self -> d_out
__global__ void node_pre(const float* __restrict__ node_input,
                         const float* __restrict__ W1_s,
                         const float* __restrict__ W1_v,
                         float* __restrict__ feat,
                         float* __restrict__ out) {
    __shared__ float lWs[32 * 64];
    __shared__ float lWv[32 * 64];
    for (int i = threadIdx.x; i < 2048; i += blockDim.x) {
        lWs[i] = W1_s[i];
        lWv[i] = W1_v[i];
    }
    __syncthreads();
    int n = blockIdx.x * blockDim.x + threadIdx.x;
    if (n >= N_NODES) return;
    const float inv_sqrt_mul = 0.17677669529663687f;  // 1/sqrt(32)
    const float a_mix = 0.9219544457292887f;          // sqrt(0.85)

    float s[32];
#pragma unroll
    for (int u = 0; u < 32; ++u) s[u] = node_input[n * 128 + u];
#pragma unroll 4
    for (int w = 0; w < 64; ++w) {
        float acc = 0.f;
#pragma unroll
        for (int u = 0; u < 32; ++u) acc += s[u] * lWs[u * 64 + w];
        acc *= inv_sqrt_mul;
        if (w < 32) feat[(size_t)n * 128 + w * 4 + 0] = acc;
        else        out[n * 128 + (w - 32)] = a_mix * acc;
    }
#pragma unroll
    for (int k = 0; k < 3; ++k) {
        float vk[32];
#pragma unroll
        for (int u = 0; u < 32; ++u) vk[u] = node_input[n * 128 + 32 + u * 3 + k];
#pragma unroll 4
        for (int w = 0; w < 64; ++w) {
            float acc = 0.f;
#pragma unroll
            for (int u = 0; u < 32; ++u) acc += vk[u] * lWv[u * 64 + w];
            acc *= inv_sqrt_mul;
            if (w < 32) feat[(size_t)n * 128 + w * 4 + 1 + k] = acc;
            else        out[n * 128 + 32 + (w - 32) * 3 + k] = a_mix * acc;
        }
    }
}

// K2a: histogram of edge_dst
__global__ void hist_kernel(const int* __restrict__ edge_dst, int* __restrict__ counts) {
    int e = blockIdx.x * blockDim.x + threadIdx.x;
    if (e < N_EDGES) atomicAdd(&counts[edge_dst[e]], 1);
}

// K2b: exclusive scan of counts -> offsets (N+1) and cursor (N). Single block.
__global__ void scan_kernel(const int* __restrict__ counts,
                            int* __restrict__ offsets,
                            int* __restrict__ cursor) {
    const int T = 1024;
    __shared__ int partial[T];
    int t = threadIdx.x;
    const int chunk = (N_NODES + T - 1) / T;
    int start = t * chunk;
    int end = start + chunk; if (end > N_NODES) end = N_NODES;
    if (start > N_NODES) start = N_NODES;
    int sum = 0;
    for (int i = start; i < end; ++i) sum += counts[i];
    partial[t] = sum;
    __syncthreads();
    for (int off = 1; off < T; off <<= 1) {
        int other = (t >= off) ? partial[t - off] : 0;
        __syncthreads();
        partial[t] += other;
        __syncthreads();
    }
    int run = (t == 0) ? 0 : partial[t - 1];
    for (int i = start; i < end; ++i) {
        offsets[i] = run;
        cursor[i] = run;
        run += counts[i];
    }
    if (t == T - 1) offsets[N_NODES] = run;  // == N_EDGES
}

// K2c: scatter edge data into dst-sorted order.
__global__ void scatter_kernel(const int* __restrict__ edge_src,
                               const int* __restrict__ edge_dst,
                               const float* __restrict__ edge_attr,
                               const float* __restrict__ edge_scalars,
                               int* __restrict__ cursor,
                               float4* __restrict__ sS4,
                               float4* __restrict__ ySorted,
                               int2* __restrict__ srcdst) {
    int e = blockIdx.x * blockDim.x + threadIdx.x;
    if (e >= N_EDGES) return;
    int d = edge_dst[e];
    int pos = atomicAdd(&cursor[d], 1);
    float4 a  = *(const float4*)(edge_attr + (size_t)e * 4);
    float4 s0 = *(const float4*)(edge_scalars + (size_t)e * 8);
    float4 s1 = *(const float4*)(edge_scalars + (size_t)e * 8 + 4);
    ySorted[pos] = a;
    sS4[(size_t)pos * 2 + 0] = s0;
    sS4[(size_t)pos * 2 + 1] = s1;
    srcdst[pos] = make_int2(edge_src[e], d);
}

// K_mlp: one THREAD per sorted edge. Transposed float4 weights in LDS
// (uniform broadcast reads). Writes w0..w3 per channel as bf16x4 (8B).
__global__ void mlp_kernel(const float4* __restrict__ sS4,
                           const float* __restrict__ M0,
                           const float* __restrict__ M1,
                           const float* __restrict__ Wtp0,
                           const float* __restrict__ Wtp1,
                           const float* __restrict__ Wtp2,
                           const float* __restrict__ Wtp3,
                           ushort4* __restrict__ wOut) {
    __shared__ float lM0t[32 * 8];        // [u][i]
    __shared__ float lM1t[32 * 32];       // [u][m]
    __shared__ float lWt[32 * 32 * 4];    // [u][j][c], c = which Wtp

    for (int idx = threadIdx.x; idx < 256; idx += blockDim.x) {
        int i = idx >> 5, u = idx & 31;
        lM0t[u * 8 + i] = M0[idx];
    }
    for (int idx = threadIdx.x; idx < 1024; idx += blockDim.x) {
        int m = idx >> 5, u = idx & 31;
        lM1t[u * 32 + m] = M1[idx];
        int base = (u * 32 + m) * 4;
        lWt[base + 0] = Wtp0[idx];
        lWt[base + 1] = Wtp1[idx];
        lWt[base + 2] = Wtp2[idx];
        lWt[base + 3] = Wtp3[idx];
    }
    __syncthreads();

    const int e = blockIdx.x * blockDim.x + threadIdx.x;
    if (e >= N_EDGES) return;

    const float inv_sqrt8  = 0.35355339059327373f;
    const float inv_sqrt32 = 0.17677669529663687f;

    const float4 s0 = sS4[(size_t)e * 2 + 0];
    const float4 s1 = sS4[(size_t)e * 2 + 1];
    const float4* lM0t4 = (const float4*)lM0t;
    const float4* lM1t4 = (const float4*)lM1t;
    const float4* lWt4  = (const float4*)lWt;

    float t[32];
#pragma unroll
    for (int u = 0; u < 32; ++u) {
        float4 a = lM0t4[u * 2 + 0];
        float4 b = lM0t4[u * 2 + 1];
        float acc = a.x * s0.x + a.y * s0.y + a.z * s0.z + a.w * s0.w
                  + b.x * s1.x + b.y * s1.y + b.z * s1.z + b.w * s1.w;
        t[u] = gelu_tanh(acc * inv_sqrt8);
    }
    float h[32];
#pragma unroll
    for (int u = 0; u < 32; ++u) {
        float acc = 0.f;
#pragma unroll
        for (int j = 0; j < 8; ++j) {
            float4 mm = lM1t4[u * 8 + j];
            acc += mm.x * t[4 * j + 0] + mm.y * t[4 * j + 1]
                 + mm.z * t[4 * j + 2] + mm.w * t[4 * j + 3];
        }
        h[u] = gelu_tanh(acc * inv_sqrt32);
    }
    ushort4* wbase = wOut + (size_t)e * 32;
#pragma unroll 1
    for (int u = 0; u < 32; ++u) {
        float ax = 0.f, ay = 0.f, az = 0.f, aw = 0.f;
#pragma unroll
        for (int j = 0; j < 32; ++j) {
            float4 wv = lWt4[u * 32 + j];
            float hj = h[j];
            ax += hj * wv.x; ay += hj * wv.y; az += hj * wv.z; aw += hj * wv.w;
        }
        ushort4 o;
        o.x = f2bf(ax * inv_sqrt32);
        o.y = f2bf(ay * inv_sqrt32);
        o.z = f2bf(az * inv_sqrt32);
        o.w = f2bf(aw * inv_sqrt32);
        wbase[u] = o;
    }
}

// K_conv: block owns NPB contiguous dst nodes => contiguous edge range.
// Each group takes a CONTIGUOUS chunk (minimizes cross-group same-address
// contention); runs of equal dst accumulate in registers and flush once
// per node via native ds_add_f32.
__global__ void __launch_bounds__(256)
conv_kernel(const ushort4* __restrict__ wOut,
            const float4* __restrict__ ySorted,
            const int2* __restrict__ srcdst,
            const int* __restrict__ offsets,
            const float* __restrict__ W2_s,
            const float* __restrict__ W2_v,
            const float* __restrict__ feat,
            float* __restrict__ out) {
    __shared__ float sacc[NPB * 256];  // per-node raw accum: [s(64) | v(3*64)]
    for (int i = threadIdx.x; i < NPB * 256; i += blockDim.x) sacc[i] = 0.f;
    __syncthreads();

    const int lane = threadIdx.x & 31;
    const int g = threadIdx.x >> 5;
    const int n0 = blockIdx.x * NPB;
    const int eb = offsets[n0];
    const int ee = offsets[n0 + NPB];
    const float INV3 = 0.5773502691896258f;  // 1/sqrt(3)
    const float4* feat4 = (const float4*)feat;

    const int total = ee - eb;
    const int per = (total + GROUPS - 1) / GROUPS;
    const int es = eb + g * per;
    int et = es + per; if (et > ee) et = ee;

    float r0 = 0.f, r1 = 0.f, r2 = 0.f, r3 = 0.f;
    float r4 = 0.f, r5 = 0.f, r6 = 0.f, r7 = 0.f;
    int cur = -1;

#pragma unroll 2
    for (int e = es; e < et; ++e) {
        const int2 sd = srcdst[e];
        const ushort4 wq = wOut[(size_t)e * 32 + lane];
        const float4 yq = ySorted[e];                  // uniform per group
        const float4 f = feat4[(size_t)sd.x * 32 + lane];

        if (sd.y != cur) {
            if (cur >= 0) {
                float* a = sacc + (cur - n0) * 256;
                lds_add(a + lane, r0);
                lds_add(a + 32 + lane, r1);
                lds_add(a + 64 + lane * 3 + 0, r2);
                lds_add(a + 64 + lane * 3 + 1, r3);
                lds_add(a + 64 + lane * 3 + 2, r4);
                lds_add(a + 160 + lane * 3 + 0, r5);
                lds_add(a + 160 + lane * 3 + 1, r6);
                lds_add(a + 160 + lane * 3 + 2, r7);
            }
            cur = sd.y;
            r0 = r1 = r2 = r3 = r4 = r5 = r6 = r7 = 0.f;
        }

        const float w0 = bf2f(wq.x), w1 = bf2f(wq.y);
        const float w2 = bf2f(wq.z), w3 = bf2f(wq.w);
        const float dvy = f.y * yq.y + f.z * yq.z + f.w * yq.w;
        const float w1es = w1 * f.x;
        const float w2y0 = w2 * yq.x;

        r0 += w0 * f.x * yq.x;
        r1 += w3 * dvy * INV3;
        r2 += w1es * yq.y;
        r3 += w1es * yq.z;
        r4 += w1es * yq.w;
        r5 += w2y0 * f.y;
        r6 += w2y0 * f.z;
        r7 += w2y0 * f.w;
    }
    if (cur >= 0) {
        float* a = sacc + (cur - n0) * 256;
        lds_add(a + lane, r0);
        lds_add(a + 32 + lane, r1);
        lds_add(a + 64 + lane * 3 + 0, r2);
        lds_add(a + 64 + lane * 3 + 1, r3);
        lds_add(a + 64 + lane * 3 + 2, r4);
        lds_add(a + 160 + lane * 3 + 0, r5);
        lds_add(a + 160 + lane * 3 + 1, r6);
        lds_add(a + 160 + lane * 3 + 2, r7);
    }
    // drain our ds_add ops before the barrier (inline asm hides them from hipcc)
    asm volatile("s_waitcnt lgkmcnt(0)" ::: "memory");
    __syncthreads();

    // epilogue: per node, conv = (acc*inv_deg) @ W2 / sqrt(64); out += sqrt(MIX)*conv
    const float scale = 0.31622776601683794f * 0.125f * 0.3872983346207417f;
    for (int li = g; li < NPB; li += GROUPS) {
        const float* a = sacc + li * 256;
        float cs = 0.f, cv0 = 0.f, cv1 = 0.f, cv2 = 0.f;
#pragma unroll 8
        for (int j = 0; j < 64; ++j) {
            const float as = a[j];                 // LDS broadcast
            cs += as * __ldg(&W2_s[j * 32 + lane]);
            const float wv = __ldg(&W2_v[j * 32 + lane]);
            cv0 += a[64 + 3 * j + 0] * wv;
            cv1 += a[64 + 3 * j + 1] * wv;
            cv2 += a[64 + 3 * j + 2] * wv;
        }
        float* o = out + (size_t)(n0 + li) * 128;
        o[lane]              += scale * cs;
        o[32 + lane * 3 + 0] += scale * cv0;
        o[32 + lane * 3 + 1] += scale * cv1;
        o[32 + lane * 3 + 2] += scale * cv2;
    }
}

extern "C" void kernel_launch(void* const* d_in, const int* in_sizes, int n_in,
                              void* d_out, int out_size, void* d_ws, size_t ws_size,
                              hipStream_t stream) {
    const float* node_input   = (const float*)d_in[0];
    const float* edge_attr    = (const float*)d_in[1];
    const float* edge_scalars = (const float*)d_in[2];
    const float* W1_s = (const float*)d_in[3];
    const float* W1_v = (const float*)d_in[4];
    const float* M0   = (const float*)d_in[5];
    const float* M1   = (const float*)d_in[6];
    const float* Wtp0 = (const float*)d_in[7];
    const float* Wtp1 = (const float*)d_in[8];
    const float* Wtp2 = (const float*)d_in[9];
    const float* Wtp3 = (const float*)d_in[10];
    const float* W2_s = (const float*)d_in[11];
    const float* W2_v = (const float*)d_in[12];
    const int* edge_src = (const int*)d_in[13];
    const int* edge_dst = (const int*)d_in[14];
    float* out = (float*)d_out;
    float* ws  = (float*)d_ws;

    float*  feat    = ws;                                           // N*128 (25.6 MB)
    float4* sS4     = (float4*)(feat + (size_t)N_NODES * 128);      // E*2 float4 (16 MB)
    float4* ySorted = sS4 + (size_t)N_EDGES * 2;                    // E float4 (8 MB)
    ushort4* wOut   = (ushort4*)(ySorted + N_EDGES);                // E*32 ushort4 (64 MB)
    int2*  srcdst   = (int2*)(wOut + (size_t)N_EDGES * 32);         // E int2 (4 MB)
    int*   counts   = (int*)(srcdst + N_EDGES);                     // N
    int*   offsets  = counts + N_NODES;                             // N+1
    int*   cursor   = offsets + N_NODES + 1;                        // N

    hipMemsetAsync(counts, 0, N_NODES * sizeof(int), stream);

    node_pre<<<(N_NODES + 255) / 256, 256, 0, stream>>>(node_input, W1_s, W1_v,
                                                        feat, out);

    hist_kernel<<<(N_EDGES + 255) / 256, 256, 0, stream>>>(edge_dst, counts);
    scan_kernel<<<1, 1024, 0, stream>>>(counts, offsets, cursor);
    scatter_kernel<<<(N_EDGES + 255) / 256, 256, 0, stream>>>(edge_src, edge_dst,
                                                              edge_attr, edge_scalars,
                                                              cursor, sS4, ySorted, srcdst);

    mlp_kernel<<<(N_EDGES + 255) / 256, 256, 0, stream>>>(sS4, M0, M1,
                                                          Wtp0, Wtp1, Wtp2, Wtp3, wOut);

    conv_kernel<<<N_NODES / NPB, 256, 0, stream>>>(wOut, ySorted, srcdst, offsets,
                                                   W2_s, W2_v, feat, out);
}